// Round 4
// baseline (216.605 us; speedup 1.0000x reference)
//
#include <hip/hip_runtime.h>
#include <math.h>

#define NROWS 16384
#define INDIM 2048
#define NE 16
#define RPB 16                    // rows per block (4 waves x 4 rows)
#define RPW 4                     // rows per wave
#define KSTEP 256                 // k covered per iteration (64 lanes x float4)
#define NITER (INDIM / KSTEP)     // 8
#define EG 4                      // experts per load-group (keeps VGPR pressure low)

__global__ __launch_bounds__(256, 4) void gate_kernel(
    const float* __restrict__ x,
    const float* __restrict__ W1,
    const float* __restrict__ W2,
    float* __restrict__ out)
{
    __shared__ float hbuf[RPB][17];
    __shared__ float w2s[NE * NE];

    const int tid  = threadIdx.x;
    const int lane = tid & 63;
    const int wv   = tid >> 6;                       // 0..3
    const int rowW = blockIdx.x * RPB + wv * RPW;    // wave's first row

    if (tid < 64) ((float4*)w2s)[tid] = ((const float4*)W2)[tid];

    // acc[r*16+e]: this lane's k-partial for (row r, expert e). Must stay in
    // VGPRs — round-3 disasm evidence: at higher peak pressure the compiler
    // moved this to AGPRs (accvgpr r/w per MAC, 2.7x VALU) and starved the
    // load pipeline. EG=4 keeps peak pressure ~108 regs < 128 cap.
    float acc[RPW * NE];
    #pragma unroll
    for (int i = 0; i < RPW * NE; ++i) acc[i] = 0.0f;

    const float* xw  = x  + (size_t)rowW * INDIM + lane * 4;  // per-lane, coalesced
    const float* w1l = W1 + lane * 4;                          // per-lane, coalesced

    #pragma unroll 1
    for (int it = 0; it < NITER; ++it) {
        const int k0 = it * KSTEP;
        float4 xv[RPW];
        #pragma unroll
        for (int r = 0; r < RPW; ++r)
            xv[r] = *(const float4*)(xw + (size_t)r * INDIM + k0);

        #pragma unroll
        for (int eg = 0; eg < NE / EG; ++eg) {
            float4 wq[EG];
            #pragma unroll
            for (int e = 0; e < EG; ++e)
                wq[e] = *(const float4*)(w1l + (size_t)(eg * EG + e) * INDIM + k0);
            #pragma unroll
            for (int r = 0; r < RPW; ++r) {
                #pragma unroll
                for (int e = 0; e < EG; ++e) {
                    float a = acc[r * NE + eg * EG + e];
                    a = fmaf(xv[r].x, wq[e].x, a);
                    a = fmaf(xv[r].y, wq[e].y, a);
                    a = fmaf(xv[r].z, wq[e].z, a);
                    a = fmaf(xv[r].w, wq[e].w, a);
                    acc[r * NE + eg * EG + e] = a;
                }
            }
        }
    }

    // ---- folding butterfly: reduce 64 values across 64 lanes in 63 shuffles.
    // After step s (mask 1<<s), lane keeps the half of its value-set selected by
    // its lane-bit s; final: lane L holds the full sum of value bitrev6(L).
    #pragma unroll
    for (int s = 0; s < 6; ++s) {
        const int m = 1 << s;
        const int h = 32 >> s;
        const int b = (lane >> s) & 1;
        #pragma unroll
        for (int i = 0; i < h; ++i) {
            const float keep = b ? acc[i + h] : acc[i];
            const float send = b ? acc[i] : acc[i + h];
            acc[i] = keep + __shfl_xor(send, m, 64);
        }
    }
    {
        int v = 0;
        #pragma unroll
        for (int s = 0; s < 6; ++s) v |= ((lane >> s) & 1) << (5 - s);
        hbuf[wv * RPW + (v >> 4)][v & 15] = tanhf(acc[0]);
    }
    __syncthreads();

    // ---- per-row tail: logits, sort, softmax, k policy, outputs ----
    if (tid < RPB) {
        const int r   = tid;
        const int row = blockIdx.x * RPB + r;

        float hr[NE];
        #pragma unroll
        for (int e = 0; e < NE; ++e) hr[e] = hbuf[r][e];

        float v[NE];
        int   idx[NE];
        #pragma unroll
        for (int f = 0; f < NE; ++f) {
            float s = 0.0f;
            #pragma unroll
            for (int j = 0; j < 4; ++j) {
                const float4 w = ((const float4*)w2s)[f * 4 + j];
                s = fmaf(hr[4 * j + 0], w.x, s);
                s = fmaf(hr[4 * j + 1], w.y, s);
                s = fmaf(hr[4 * j + 2], w.z, s);
                s = fmaf(hr[4 * j + 3], w.w, s);
            }
            v[f]   = s / 0.7f;
            idx[f] = f;
        }

        // bitonic sort on key (-value, index): stable descending argsort
        #pragma unroll
        for (int ksz = 2; ksz <= 16; ksz <<= 1) {
            #pragma unroll
            for (int jsz = ksz >> 1; jsz >= 1; jsz >>= 1) {
                #pragma unroll
                for (int i = 0; i < 16; ++i) {
                    const int l = i ^ jsz;
                    if (l > i) {
                        const bool asc   = ((i & ksz) == 0);
                        const bool keyGt = (v[i] < v[l]) ||
                                           (v[i] == v[l] && idx[i] > idx[l]);
                        if (keyGt == asc) {
                            float tv = v[i]; v[i] = v[l]; v[l] = tv;
                            int   ti = idx[i]; idx[i] = idx[l]; idx[l] = ti;
                        }
                    }
                }
            }
        }

        float p[NE];
        float tot = 0.0f;
        #pragma unroll
        for (int i = 0; i < NE; ++i) { p[i] = expf(v[i] - v[0]); tot += p[i]; }
        #pragma unroll
        for (int i = 0; i < NE; ++i) p[i] = p[i] / tot;

        float cum[NE];
        cum[0] = p[0];
        #pragma unroll
        for (int i = 1; i < NE; ++i) cum[i] = cum[i - 1] + p[i];

        int k = NE;
        #pragma unroll
        for (int i = NE - 1; i >= 0; --i) if (cum[i] >= 0.92f) k = i + 1;

        if ((p[0] >= 0.46f) && ((p[0] - p[1]) >= 0.1f)) k = 1;
        if ((k > 2) && ((cum[1] >= 0.82f) || (p[2] <= 0.12f) || ((p[1] - p[2]) <= 0.03f)))
            k = 2;
        k = k < 1 ? 1 : (k > 3 ? 3 : k);

        const float4 o0 = make_float4((float)idx[0], (float)idx[1], (float)idx[2], (float)idx[3]);
        const float4 o1 = make_float4((float)idx[4], (float)idx[5], (float)idx[6], (float)idx[7]);
        const float4 s0 = make_float4(k > 0 ? p[0] : 0.0f, k > 1 ? p[1] : 0.0f,
                                      k > 2 ? p[2] : 0.0f, k > 3 ? p[3] : 0.0f);
        const float4 s1 = make_float4(k > 4 ? p[4] : 0.0f, k > 5 ? p[5] : 0.0f,
                                      k > 6 ? p[6] : 0.0f, k > 7 ? p[7] : 0.0f);
        const float4 m0 = make_float4(k > 0 ? 1.0f : 0.0f, k > 1 ? 1.0f : 0.0f,
                                      k > 2 ? 1.0f : 0.0f, k > 3 ? 1.0f : 0.0f);
        const float4 m1 = make_float4(k > 4 ? 1.0f : 0.0f, k > 5 ? 1.0f : 0.0f,
                                      k > 6 ? 1.0f : 0.0f, k > 7 ? 1.0f : 0.0f);

        float4* oI = (float4*)(out + (size_t)row * 8);
        float4* oS = (float4*)(out + (size_t)NROWS * 8  + (size_t)row * 8);
        float4* oM = (float4*)(out + (size_t)NROWS * 16 + (size_t)row * 8);
        oI[0] = o0; oI[1] = o1;
        oS[0] = s0; oS[1] = s1;
        oM[0] = m0; oM[1] = m1;
        out[(size_t)NROWS * 24 + row] = (float)k;
    }
}

extern "C" void kernel_launch(void* const* d_in, const int* in_sizes, int n_in,
                              void* d_out, int out_size, void* d_ws, size_t ws_size,
                              hipStream_t stream)
{
    const float* x  = (const float*)d_in[0];
    const float* W1 = (const float*)d_in[1];
    const float* W2 = (const float*)d_in[2];
    gate_kernel<<<NROWS / RPB, 256, 0, stream>>>(x, W1, W2, (float*)d_out);
}

// Round 5
// 206.127 us; speedup vs baseline: 1.0508x; 1.0508x over previous
//
#include <hip/hip_runtime.h>
#include <math.h>

#define NROWS 16384
#define INDIM 2048
#define NE 16
#define RPB 16                    // rows per block (4 waves x 4 rows)
#define RPW 4                     // rows per wave
#define KSTEP 256                 // k covered per iteration (64 lanes x float4)
#define NITER (INDIM / KSTEP)     // 8

// launch_bounds(256,2): 256-VGPR cap. Round-4 evidence: at (256,4) the 128-reg
// cap forced acc into AGPRs (VGPR_Count=56, accvgpr tax 2.7x VALU) and left no
// registers to pipeline loads (near-serialized vmcnt waits, 78us @ 11% HBM).
__global__ __launch_bounds__(256, 2) void gate_kernel(
    const float* __restrict__ x,
    const float* __restrict__ W1,
    const float* __restrict__ W2,
    float* __restrict__ out)
{
    __shared__ float hbuf[RPB][17];
    __shared__ float w2s[NE * NE];

    const int tid  = threadIdx.x;
    const int lane = tid & 63;
    const int wv   = tid >> 6;                       // 0..3
    const int rowW = blockIdx.x * RPB + wv * RPW;    // wave's first row

    if (tid < 64) ((float4*)w2s)[tid] = ((const float4*)W2)[tid];

    float acc[RPW * NE];
    #pragma unroll
    for (int i = 0; i < RPW * NE; ++i) acc[i] = 0.0f;

    const float* xw  = x  + (size_t)rowW * INDIM + lane * 4;  // per-lane, coalesced
    const float* w1l = W1 + lane * 4;                          // per-lane, coalesced

    // ---- explicit software pipeline ----
    float4 xv_cur[RPW], xv_nxt[RPW];
    float4 wq_a[8], wq_b[8];   // expert-halves 0-7 / 8-15

    #pragma unroll
    for (int r = 0; r < RPW; ++r)
        xv_cur[r] = *(const float4*)(xw + (size_t)r * INDIM);
    #pragma unroll
    for (int e = 0; e < 8; ++e)
        wq_a[e] = *(const float4*)(w1l + (size_t)e * INDIM);

    #pragma unroll 1
    for (int it = 0; it < NITER; ++it) {
        const int k1 = (it + 1) * KSTEP;

        // prefetch next-iteration x (covers HBM latency: awaited ~1 iter later)
        if (it + 1 < NITER) {
            #pragma unroll
            for (int r = 0; r < RPW; ++r)
                xv_nxt[r] = *(const float4*)(xw + (size_t)r * INDIM + k1);
        }
        // prefetch expert-half B of THIS iteration, then compute half A
        #pragma unroll
        for (int e = 0; e < 8; ++e)
            wq_b[e] = *(const float4*)(w1l + (size_t)(8 + e) * INDIM + it * KSTEP);
        #pragma unroll
        for (int r = 0; r < RPW; ++r) {
            #pragma unroll
            for (int e = 0; e < 8; ++e) {
                float a = acc[r * NE + e];
                a = fmaf(xv_cur[r].x, wq_a[e].x, a);
                a = fmaf(xv_cur[r].y, wq_a[e].y, a);
                a = fmaf(xv_cur[r].z, wq_a[e].z, a);
                a = fmaf(xv_cur[r].w, wq_a[e].w, a);
                acc[r * NE + e] = a;
            }
        }
        // prefetch expert-half A of NEXT iteration, then compute half B
        if (it + 1 < NITER) {
            #pragma unroll
            for (int e = 0; e < 8; ++e)
                wq_a[e] = *(const float4*)(w1l + (size_t)e * INDIM + k1);
        }
        #pragma unroll
        for (int r = 0; r < RPW; ++r) {
            #pragma unroll
            for (int e = 0; e < 8; ++e) {
                float a = acc[r * NE + 8 + e];
                a = fmaf(xv_cur[r].x, wq_b[e].x, a);
                a = fmaf(xv_cur[r].y, wq_b[e].y, a);
                a = fmaf(xv_cur[r].z, wq_b[e].z, a);
                a = fmaf(xv_cur[r].w, wq_b[e].w, a);
                acc[r * NE + 8 + e] = a;
            }
        }
        #pragma unroll
        for (int r = 0; r < RPW; ++r) xv_cur[r] = xv_nxt[r];
    }

    // ---- folding butterfly: reduce 64 values across 64 lanes in 63 shuffles ----
    #pragma unroll
    for (int s = 0; s < 6; ++s) {
        const int m = 1 << s;
        const int h = 32 >> s;
        const int b = (lane >> s) & 1;
        #pragma unroll
        for (int i = 0; i < h; ++i) {
            const float keep = b ? acc[i + h] : acc[i];
            const float send = b ? acc[i] : acc[i + h];
            acc[i] = keep + __shfl_xor(send, m, 64);
        }
    }
    {
        int v = 0;
        #pragma unroll
        for (int s = 0; s < 6; ++s) v |= ((lane >> s) & 1) << (5 - s);
        hbuf[wv * RPW + (v >> 4)][v & 15] = tanhf(acc[0]);
    }
    __syncthreads();

    // ---- per-row tail: logits, sort, softmax, k policy, outputs ----
    if (tid < RPB) {
        const int r   = tid;
        const int row = blockIdx.x * RPB + r;

        float hr[NE];
        #pragma unroll
        for (int e = 0; e < NE; ++e) hr[e] = hbuf[r][e];

        float v[NE];
        int   idx[NE];
        #pragma unroll
        for (int f = 0; f < NE; ++f) {
            float s = 0.0f;
            #pragma unroll
            for (int j = 0; j < 4; ++j) {
                const float4 w = ((const float4*)w2s)[f * 4 + j];
                s = fmaf(hr[4 * j + 0], w.x, s);
                s = fmaf(hr[4 * j + 1], w.y, s);
                s = fmaf(hr[4 * j + 2], w.z, s);
                s = fmaf(hr[4 * j + 3], w.w, s);
            }
            v[f]   = s / 0.7f;
            idx[f] = f;
        }

        // bitonic sort on key (-value, index): stable descending argsort
        #pragma unroll
        for (int ksz = 2; ksz <= 16; ksz <<= 1) {
            #pragma unroll
            for (int jsz = ksz >> 1; jsz >= 1; jsz >>= 1) {
                #pragma unroll
                for (int i = 0; i < 16; ++i) {
                    const int l = i ^ jsz;
                    if (l > i) {
                        const bool asc   = ((i & ksz) == 0);
                        const bool keyGt = (v[i] < v[l]) ||
                                           (v[i] == v[l] && idx[i] > idx[l]);
                        if (keyGt == asc) {
                            float tv = v[i]; v[i] = v[l]; v[l] = tv;
                            int   ti = idx[i]; idx[i] = idx[l]; idx[l] = ti;
                        }
                    }
                }
            }
        }

        float p[NE];
        float tot = 0.0f;
        #pragma unroll
        for (int i = 0; i < NE; ++i) { p[i] = expf(v[i] - v[0]); tot += p[i]; }
        #pragma unroll
        for (int i = 0; i < NE; ++i) p[i] = p[i] / tot;

        float cum[NE];
        cum[0] = p[0];
        #pragma unroll
        for (int i = 1; i < NE; ++i) cum[i] = cum[i - 1] + p[i];

        int k = NE;
        #pragma unroll
        for (int i = NE - 1; i >= 0; --i) if (cum[i] >= 0.92f) k = i + 1;

        if ((p[0] >= 0.46f) && ((p[0] - p[1]) >= 0.1f)) k = 1;
        if ((k > 2) && ((cum[1] >= 0.82f) || (p[2] <= 0.12f) || ((p[1] - p[2]) <= 0.03f)))
            k = 2;
        k = k < 1 ? 1 : (k > 3 ? 3 : k);

        const float4 o0 = make_float4((float)idx[0], (float)idx[1], (float)idx[2], (float)idx[3]);
        const float4 o1 = make_float4((float)idx[4], (float)idx[5], (float)idx[6], (float)idx[7]);
        const float4 s0 = make_float4(k > 0 ? p[0] : 0.0f, k > 1 ? p[1] : 0.0f,
                                      k > 2 ? p[2] : 0.0f, k > 3 ? p[3] : 0.0f);
        const float4 s1 = make_float4(k > 4 ? p[4] : 0.0f, k > 5 ? p[5] : 0.0f,
                                      k > 6 ? p[6] : 0.0f, k > 7 ? p[7] : 0.0f);
        const float4 m0 = make_float4(k > 0 ? 1.0f : 0.0f, k > 1 ? 1.0f : 0.0f,
                                      k > 2 ? 1.0f : 0.0f, k > 3 ? 1.0f : 0.0f);
        const float4 m1 = make_float4(k > 4 ? 1.0f : 0.0f, k > 5 ? 1.0f : 0.0f,
                                      k > 6 ? 1.0f : 0.0f, k > 7 ? 1.0f : 0.0f);

        float4* oI = (float4*)(out + (size_t)row * 8);
        float4* oS = (float4*)(out + (size_t)NROWS * 8  + (size_t)row * 8);
        float4* oM = (float4*)(out + (size_t)NROWS * 16 + (size_t)row * 8);
        oI[0] = o0; oI[1] = o1;
        oS[0] = s0; oS[1] = s1;
        oM[0] = m0; oM[1] = m1;
        out[(size_t)NROWS * 24 + row] = (float)k;
    }
}

extern "C" void kernel_launch(void* const* d_in, const int* in_sizes, int n_in,
                              void* d_out, int out_size, void* d_ws, size_t ws_size,
                              hipStream_t stream)
{
    const float* x  = (const float*)d_in[0];
    const float* W1 = (const float*)d_in[1];
    const float* W2 = (const float*)d_in[2];
    gate_kernel<<<NROWS / RPB, 256, 0, stream>>>(x, W1, W2, (float*)d_out);
}